// Round 3
// baseline (435.071 us; speedup 1.0000x reference)
//
#include <hip/hip_runtime.h>
#include <cstdint>
#include <cstddef>

#define NAG 32
#define NF 528
#define HD 64
#define SD 512

typedef __attribute__((ext_vector_type(8))) short bf16x8;
typedef __attribute__((ext_vector_type(4))) float f32x4;
#define MFMA16(a, b, c) __builtin_amdgcn_mfma_f32_16x16x32_bf16(a, b, c, 0, 0, 0)

__device__ __forceinline__ unsigned short f2bf(float f) {
    unsigned int u = __float_as_uint(f);
    u += 0x7fffu + ((u >> 16) & 1u);
    return (unsigned short)(u >> 16);
}
__device__ __forceinline__ unsigned int pack2(float a, float b) {
    return (unsigned int)f2bf(a) | ((unsigned int)f2bf(b) << 16);
}
__device__ __forceinline__ bf16x8 pack8(float4 v0, float4 v1) {
    union { bf16x8 v; unsigned int u[4]; } r;
    r.u[0] = pack2(v0.x, v0.y);
    r.u[1] = pack2(v0.z, v0.w);
    r.u[2] = pack2(v1.x, v1.y);
    r.u[3] = pack2(v1.z, v1.w);
    return r.v;
}
__device__ __forceinline__ float elu_f(float x) {
    return x > 0.f ? x : (__expf(x) - 1.f);
}
__device__ __forceinline__ float4 abs4(float4 v) {
    return make_float4(fabsf(v.x), fabsf(v.y), fabsf(v.z), fabsf(v.w));
}

// ---- d_ws layout (ushort/bf16): wsT[64][512], wb1T[64][512], wzT[64][512],
//      wa1T[64][128], wa2T[528][64]; then packed pair LUT (int[496]) after.
#define OFF_WST   0
#define OFF_WB1T  32768
#define OFF_WZT   65536
#define OFF_WA1T  98304
#define OFF_WA2T  106496
#define PREP_TOT  140288
#define OFF_LUT_BYTES (PREP_TOT * 2)   // 280576, int pair-LUT pi*64+pj

// ---------------- Kernel 0: weight transpose + bf16 convert + pair LUT ----------------
__global__ __launch_bounds__(256) void prep_kernel(
    const float* __restrict__ ws_w, const float* __restrict__ wb1_w,
    const float* __restrict__ wz_w, const float* __restrict__ wa1_w,
    const float* __restrict__ wa2_w, unsigned short* __restrict__ ws,
    int* __restrict__ lut)
{
    int i = blockIdx.x * 256 + threadIdx.x;
    if (i < 496) {
        int p = i, a = 0, c = NAG - 1;
        while (p >= c) { p -= c; c--; a++; }
        lut[i] = a * 64 + (a + 1 + p);
    }
    if (i >= PREP_TOT) return;
    float v;
    if (i < OFF_WB1T) {
        int j = i - OFF_WST; int n = j >> 9, k = j & 511;
        v = ws_w[k * 64 + n];
    } else if (i < OFF_WZT) {
        int j = i - OFF_WB1T; int n = j >> 9, k = j & 511;
        v = wb1_w[k * 64 + n];
    } else if (i < OFF_WA1T) {
        int j = i - OFF_WZT; int n = j >> 9, k = j & 511;
        v = wz_w[k * 64 + n];
    } else if (i < OFF_WA2T) {
        int j = i - OFF_WA1T; int n = j >> 7, k = j & 127;
        v = wa1_w[k * 64 + n];
    } else {
        int j = i - OFF_WA2T; int n = j >> 6, k = j & 63;
        v = wa2_w[k * NF + n];
    }
    ws[i] = f2bf(v);
}

// ---------------- Fused kernel: everything, barrier-free ----------------
// 4 waves/block; wave w owns rows [blockIdx*64 + 16w, +16) end-to-end.
// A-frag: lane holds A[m=col][k=quad*8+j] loaded DIRECTLY from global (fp32->bf16
// in regs). D-layout: row=quad*4+reg, col=lane&15. Per-wave-private LDS only
// (q tile + fragment transposes) -> zero __syncthreads.
__global__ __launch_bounds__(256, 2) void fused_kernel(
    const float* __restrict__ q,
    const float* __restrict__ state,
    const float* __restrict__ sem,
    const unsigned short* __restrict__ wsbuf,
    const int* __restrict__ lut,
    const float* __restrict__ w1_1, const float* __restrict__ b1_1,
    const float* __restrict__ w2_1, const float* __restrict__ b2_1,
    const float* __restrict__ w3_1, const float* __restrict__ b3_1,
    const float* __restrict__ w1_2, const float* __restrict__ b1_2,
    const float* __restrict__ w2_2, const float* __restrict__ b2_2,
    const float* __restrict__ w3_2, const float* __restrict__ b3_2,
    const float* __restrict__ ws_b, const float* __restrict__ wz_b,
    const float* __restrict__ wa1_b, const float* __restrict__ wa2_b,
    const float* __restrict__ wb1_b, const float* __restrict__ wb2_w,
    const float* __restrict__ wb2_b,
    float* __restrict__ q_total,
    float* __restrict__ attn_out,
    float* __restrict__ shape_out)
{
    __shared__ float qs[4][16][36];               // per-wave q tile, 16B-aligned rows
    __shared__ unsigned short sComb[4][16][136];  // per-wave [relu(C1)|relu(C3)]
    __shared__ unsigned short sH[4][16][72];      // per-wave relu(C4)

    const unsigned short* wsT  = wsbuf + OFF_WST;
    const unsigned short* wb1T = wsbuf + OFF_WB1T;
    const unsigned short* wzT  = wsbuf + OFF_WZT;
    const unsigned short* wa1T = wsbuf + OFF_WA1T;
    const unsigned short* wa2T = wsbuf + OFF_WA2T;

    int tid  = threadIdx.x;
    int lane = tid & 63;
    int w    = tid >> 6;
    int col  = lane & 15;
    int quad = lane >> 4;
    int rw   = blockIdx.x * 64 + w * 16;   // wave's first global row

    // ---- stage q tile (own rows only, no barrier) ----
    #pragma unroll
    for (int i = 0; i < 2; i++) {
        int idx = i * 64 + lane;              // float4 index 0..127
        int r = idx >> 3, c = (idx & 7) * 4;
        float4 v = *(const float4*)&q[(size_t)(rw + r) * NAG + c];
        *(float4*)&qs[w][r][c] = v;
    }

    // ---- encoders: state -> C1(ws),C2(wb1); sem -> C3(wz) ----
    f32x4 accS[4], accB[4], accZ[4];
    #pragma unroll
    for (int ct = 0; ct < 4; ct++) {
        accS[ct] = (f32x4){0.f,0.f,0.f,0.f};
        accB[ct] = (f32x4){0.f,0.f,0.f,0.f};
        accZ[ct] = (f32x4){0.f,0.f,0.f,0.f};
    }

    const float* As = state + (size_t)(rw + col) * SD + quad * 8;
    const float* Az = sem   + (size_t)(rw + col) * SD + quad * 8;

    #pragma unroll 4
    for (int ks = 0; ks < 16; ks++) {
        float4 v0 = *(const float4*)(As + ks * 32);
        float4 v1 = *(const float4*)(As + ks * 32 + 4);
        bf16x8 a = pack8(v0, v1);
        int wof = ks * 32 + quad * 8;
        #pragma unroll
        for (int ct = 0; ct < 4; ct++) {
            bf16x8 bS = *(const bf16x8*)&wsT [(ct * 16 + col) * SD + wof];
            bf16x8 bB = *(const bf16x8*)&wb1T[(ct * 16 + col) * SD + wof];
            accS[ct] = MFMA16(a, bS, accS[ct]);
            accB[ct] = MFMA16(a, bB, accB[ct]);
        }
    }
    #pragma unroll 4
    for (int ks = 0; ks < 16; ks++) {
        float4 v0 = *(const float4*)(Az + ks * 32);
        float4 v1 = *(const float4*)(Az + ks * 32 + 4);
        bf16x8 a = pack8(v0, v1);
        int wof = ks * 32 + quad * 8;
        #pragma unroll
        for (int ct = 0; ct < 4; ct++) {
            bf16x8 bZ = *(const bf16x8*)&wzT[(ct * 16 + col) * SD + wof];
            accZ[ct] = MFMA16(a, bZ, accZ[ct]);
        }
    }

    // ---- comb = [relu(C1+ws_b) | relu(C3+wz_b)] -> per-wave LDS ----
    #pragma unroll
    for (int ct = 0; ct < 4; ct++) {
        float bs = ws_b[ct * 16 + col];
        float bz = wz_b[ct * 16 + col];
        #pragma unroll
        for (int reg = 0; reg < 4; reg++) {
            int rr = quad * 4 + reg;
            sComb[w][rr][ct * 16 + col]      = f2bf(fmaxf(accS[ct][reg] + bs, 0.f));
            sComb[w][rr][64 + ct * 16 + col] = f2bf(fmaxf(accZ[ct][reg] + bz, 0.f));
        }
    }

    // ---- bias head: qb = relu(C2+wb1_b) @ wb2_w ----
    float qbv[4];
    #pragma unroll
    for (int reg = 0; reg < 4; reg++) {
        float p = 0.f;
        #pragma unroll
        for (int ct = 0; ct < 4; ct++)
            p += fmaxf(accB[ct][reg] + wb1_b[ct * 16 + col], 0.f) * wb2_w[ct * 16 + col];
        #pragma unroll
        for (int m = 1; m < 16; m <<= 1) p += __shfl_xor(p, m, 64);
        qbv[reg] = p;
    }

    // ---- C4 = comb @ wa1, relu -> sH ----
    f32x4 accH[4];
    #pragma unroll
    for (int ct = 0; ct < 4; ct++) accH[ct] = (f32x4){0.f,0.f,0.f,0.f};
    #pragma unroll
    for (int ks = 0; ks < 4; ks++) {
        bf16x8 a = *(const bf16x8*)&sComb[w][col][ks * 32 + quad * 8];
        #pragma unroll
        for (int ct = 0; ct < 4; ct++) {
            bf16x8 b = *(const bf16x8*)&wa1T[(ct * 16 + col) * 128 + ks * 32 + quad * 8];
            accH[ct] = MFMA16(a, b, accH[ct]);
        }
    }
    #pragma unroll
    for (int ct = 0; ct < 4; ct++) {
        float bh = wa1_b[ct * 16 + col];
        #pragma unroll
        for (int reg = 0; reg < 4; reg++)
            sH[w][quad * 4 + reg][ct * 16 + col] = f2bf(fmaxf(accH[ct][reg] + bh, 0.f));
    }

    bf16x8 ha0 = *(const bf16x8*)&sH[w][col][quad * 8];
    bf16x8 ha1 = *(const bf16x8*)&sH[w][col][32 + quad * 8];

    // ---- pass 1: logits tile + fused shape functions + online softmax accum ----
    union F8  { float4 v[2]; float f[8];  };
    union F32 { float4 v[8]; float f[32]; };
    union F4  { float4 v;    float f[4];  };

    float sAcc[4] = {0.f,0.f,0.f,0.f};
    float wAcc[4] = {0.f,0.f,0.f,0.f};

    #pragma unroll 1
    for (int nt = 0; nt < 33; nt++) {
        f32x4 acc = (f32x4){0.f,0.f,0.f,0.f};
        const unsigned short* wp = &wa2T[(nt * 16 + col) * 64 + quad * 8];
        acc = MFMA16(ha0, *(const bf16x8*)wp, acc);
        acc = MFMA16(ha1, *(const bf16x8*)(wp + 32), acc);
        float lb = wa2_b[nt * 16 + col];

        int f = nt * 16 + col;
        F8 W1A, W1B, B1; F32 W2; F4 B2, W3; float b3v;
        int pi, pj;
        if (nt < 2) {
            int n = f;
            pi = n; pj = n;
            const float4* p = (const float4*)(w1_1 + n * 8);
            W1A.v[0] = abs4(p[0]); W1A.v[1] = abs4(p[1]);
            W1B.v[0] = make_float4(0.f,0.f,0.f,0.f); W1B.v[1] = W1B.v[0];
            const float4* pb = (const float4*)(b1_1 + n * 8);
            B1.v[0] = pb[0]; B1.v[1] = pb[1];
            const float4* p2 = (const float4*)(w2_1 + n * 32);
            #pragma unroll
            for (int t = 0; t < 8; t++) W2.v[t] = abs4(p2[t]);
            B2.v = *(const float4*)(b2_1 + n * 4);
            W3.v = abs4(*(const float4*)(w3_1 + n * 4));
            b3v = b3_1[n];
        } else {
            int n = f - 32;
            int pk = lut[n];
            pi = pk >> 6; pj = pk & 63;
            const float4* p = (const float4*)(w1_2 + n * 16);
            W1A.v[0] = abs4(p[0]); W1A.v[1] = abs4(p[1]);
            W1B.v[0] = abs4(p[2]); W1B.v[1] = abs4(p[3]);
            const float4* pb = (const float4*)(b1_2 + n * 8);
            B1.v[0] = pb[0]; B1.v[1] = pb[1];
            const float4* p2 = (const float4*)(w2_2 + n * 32);
            #pragma unroll
            for (int t = 0; t < 8; t++) W2.v[t] = abs4(p2[t]);
            B2.v = *(const float4*)(b2_2 + n * 4);
            W3.v = abs4(*(const float4*)(w3_2 + n * 4));
            b3v = b3_2[n];
        }

        #pragma unroll
        for (int reg = 0; reg < 4; reg++) {
            int rl = quad * 4 + reg;
            float qi = qs[w][rl][pi];
            float qj = qs[w][rl][pj];
            float h1[8];
            #pragma unroll
            for (int k = 0; k < 8; k++)
                h1[k] = elu_f(W1A.f[k] * qi + W1B.f[k] * qj + B1.f[k]);
            float h2[4];
            #pragma unroll
            for (int j = 0; j < 4; j++) {
                float a2 = B2.f[j];
                #pragma unroll
                for (int k = 0; k < 8; k++) a2 += h1[k] * W2.f[k * 4 + j];
                h2[j] = elu_f(a2);
            }
            float fv = b3v;
            #pragma unroll
            for (int j = 0; j < 4; j++) fv += h2[j] * W3.f[j];

            shape_out[(size_t)(rw + rl) * NF + f] = fv;
            float e = __expf(acc[reg] + lb);
            sAcc[reg] += e;
            wAcc[reg] += e * fv;
        }
    }

    // ---- softmax denom + q_total ----
    float inv[4];
    float wb2b0 = wb2_b[0];
    #pragma unroll
    for (int reg = 0; reg < 4; reg++) {
        float s = sAcc[reg], ww = wAcc[reg];
        #pragma unroll
        for (int m = 1; m < 16; m <<= 1) { s += __shfl_xor(s, m, 64); ww += __shfl_xor(ww, m, 64); }
        inv[reg] = 1.f / s;
        if (col == 0)
            q_total[rw + quad * 4 + reg] = ww * inv[reg] + qbv[reg] + wb2b0;
    }

    // ---- pass 2: recompute logits, write normalized attention ----
    #pragma unroll 1
    for (int nt = 0; nt < 33; nt++) {
        f32x4 acc = (f32x4){0.f,0.f,0.f,0.f};
        const unsigned short* wp = &wa2T[(nt * 16 + col) * 64 + quad * 8];
        acc = MFMA16(ha0, *(const bf16x8*)wp, acc);
        acc = MFMA16(ha1, *(const bf16x8*)(wp + 32), acc);
        float lb = wa2_b[nt * 16 + col];
        #pragma unroll
        for (int reg = 0; reg < 4; reg++) {
            float e = __expf(acc[reg] + lb);
            attn_out[(size_t)(rw + quad * 4 + reg) * NF + nt * 16 + col] = e * inv[reg];
        }
    }
}

extern "C" void kernel_launch(void* const* d_in, const int* in_sizes, int n_in,
                              void* d_out, int out_size, void* d_ws, size_t ws_size,
                              hipStream_t stream) {
    const float* q     = (const float*)d_in[0];
    const float* state = (const float*)d_in[1];
    const float* sem   = (const float*)d_in[2];
    const float* w1_1  = (const float*)d_in[3];
    const float* b1_1  = (const float*)d_in[4];
    const float* w2_1  = (const float*)d_in[5];
    const float* b2_1  = (const float*)d_in[6];
    const float* w3_1  = (const float*)d_in[7];
    const float* b3_1  = (const float*)d_in[8];
    const float* w1_2  = (const float*)d_in[9];
    const float* b1_2  = (const float*)d_in[10];
    const float* w2_2  = (const float*)d_in[11];
    const float* b2_2  = (const float*)d_in[12];
    const float* w3_2  = (const float*)d_in[13];
    const float* b3_2  = (const float*)d_in[14];
    const float* ws_w  = (const float*)d_in[15];
    const float* ws_b  = (const float*)d_in[16];
    const float* wz_w  = (const float*)d_in[17];
    const float* wz_b  = (const float*)d_in[18];
    const float* wa1_w = (const float*)d_in[19];
    const float* wa1_b = (const float*)d_in[20];
    const float* wa2_w = (const float*)d_in[21];
    const float* wa2_b = (const float*)d_in[22];
    const float* wb1_w = (const float*)d_in[23];
    const float* wb1_b = (const float*)d_in[24];
    const float* wb2_w = (const float*)d_in[25];
    const float* wb2_b = (const float*)d_in[26];

    int B = in_sizes[0] / NAG;

    float* out_q    = (float*)d_out;                 // [B]
    float* out_attn = out_q + B;                     // [B, NF]
    float* out_shp  = out_attn + (size_t)B * NF;     // [B, NF]

    unsigned short* wsbuf = (unsigned short*)d_ws;
    int* lut = (int*)((char*)d_ws + OFF_LUT_BYTES);

    prep_kernel<<<(PREP_TOT + 255) / 256, 256, 0, stream>>>(
        ws_w, wb1_w, wz_w, wa1_w, wa2_w, wsbuf, lut);

    fused_kernel<<<B / 64, 256, 0, stream>>>(q, state, sem, wsbuf, lut,
        w1_1, b1_1, w2_1, b2_1, w3_1, b3_1,
        w1_2, b1_2, w2_2, b2_2, w3_2, b3_2,
        ws_b, wz_b, wa1_b, wa2_b, wb1_b, wb2_w, wb2_b,
        out_q, out_attn, out_shp);
}